// Round 2
// baseline (77.392 us; speedup 1.0000x reference)
//
#include <hip/hip_runtime.h>

typedef float v2f __attribute__((ext_vector_type(2)));

#if defined(__has_builtin) && __has_builtin(__builtin_amdgcn_exp2f)
#  define FAST_EXP2(x) __builtin_amdgcn_exp2f(x)
#else
#  define FAST_EXP2(x) exp2f(x)
#endif

// out[b,p,0] =  sum_v tau_v * exp(-r2/sig^2) * rsqrt(r2) * (p1 - x_v)
// out[b,p,1] = -sum_v tau_v * exp(-r2/sig^2) * rsqrt(r2) * (p0 - y_v)
//
// Coordinate pre-scaling (a = sqrt(log2e)/|sig|): dy' = a*(p0-y),
// dx' = a*(p1-x), r2' = dy'^2+dx'^2 -> exp(-r2/sig^2)*rsqrt(r2)*dx =
// exp2(-r2')*rsqrt(r2')*dx' (a cancels); exp negation via src modifier.
//
// R5 theory: measured ~300 cyc/iter fits "wave64 trans op ~32 issue cyc"
// (8 trans/iter = 256 cyc dominates 16 pk-VALU = 32 cyc). So: move the
// 4 v_rsq_f32 per iter OFF the trans pipe -> magic-seed + 2-Newton
// inverse sqrt on pk VALU (adds ~88 VALU cyc, removes ~128 trans cyc).
// Rel err ~4.5e-6, negligible vs absmax 1.6e-2 on O(1) outputs.
// (R6: identical resubmit — R5 bench was an infra failure, no data.)
__device__ __forceinline__ v2f rsq_nr2(v2f x) {
    v2f y;
    y.x = __int_as_float(0x5f375a86 - (__float_as_int(x.x) >> 1));
    y.y = __int_as_float(0x5f375a86 - (__float_as_int(x.y) >> 1));
    const v2f xh = x * -0.5f;          // v_pk_mul_f32
    y = y * (xh * y * y + 1.5f);       // 2x pk (mul+fma) + pk mul
    y = y * (xh * y * y + 1.5f);
    return y;
}

// 4 points/thread (two v2f groups -> v_pk_*_f32) so each ds_read_b128
// broadcast serves 4 points. Split-K x8: 512 blocks x 512 threads; wave q
// covers vortices [64q,64q+64) for the block's 256 points. 4096 waves =
// 4 waves/SIMD (occupancy proven non-binding in R4).
__global__ __launch_bounds__(512, 4)
void GaussianFalloffKernel_83434034692733_kernel(
    const float* __restrict__ vortex,   // (2, 512, 6)
    const float* __restrict__ points,   // (2, 65536, 2)
    float* __restrict__ out)            // (2, 65536, 2)
{
    constexpr int NV  = 512;
    constexpr int NQ  = 8;                 // split-K pieces (= waves/block)
    constexpr int VQ  = NV / NQ;           // 64 vortices per wave
    constexpr int PTS = 256;               // points per block (64 lanes x 4)
    constexpr int BPB = 65536 / PTS;       // 256 blocks per batch

    __shared__ float4 sv[NV];              // {a, -a*y, -a*x, tau}, 8 KB
    __shared__ v2f    red[NQ][PTS];        // 16 KB cross-wave partials

    const int b    = blockIdx.x / BPB;
    const int base = (blockIdx.x % BPB) * PTS;
    const int tid  = threadIdx.x;
    const int q    = tid >> 6;             // wave index == vortex slice
    const int h    = tid & 63;             // lane

    // Stage: one vortex per thread (512 threads, 512 vortices).
    {
        const float* __restrict__ p = vortex + ((size_t)b * NV + tid) * 6;
        const float y   = p[0];
        const float x   = p[1];
        const float tau = p[2];
        const float sig = p[3];
        const float a   = 1.2011224087864498f / fabsf(sig);  // sqrt(log2e)/|sig|
        sv[tid] = make_float4(a, -a * y, -a * x, tau);
    }
    __syncthreads();

    // Four points per thread: base + h + {0,64,128,192}, packed SoA.
    const float2* __restrict__ pp =
        (const float2*)points + (size_t)b * 65536 + base;
    const float2 p0 = pp[h];
    const float2 p1 = pp[h + 64];
    const float2 p2 = pp[h + 128];
    const float2 p3 = pp[h + 192];
    const v2f pyA = { p0.x, p1.x }, pxA = { p0.y, p1.y };
    const v2f pyB = { p2.x, p3.x }, pxB = { p2.y, p3.y };

    v2f acc0A = { 0.0f, 0.0f }, acc1A = { 0.0f, 0.0f };
    v2f acc0B = { 0.0f, 0.0f }, acc1B = { 0.0f, 0.0f };

    const float4* __restrict__ svq = sv + q * VQ;
    #pragma unroll 4
    for (int v = 0; v < VQ; ++v) {
        const float4 s = svq[v];              // wave-uniform LDS broadcast
        const v2f dyA = pyA * s.x + s.y;      // a*(p0 - y_v)   (pk_fma)
        const v2f dxA = pxA * s.x + s.z;      // a*(p1 - x_v)
        const v2f dyB = pyB * s.x + s.y;
        const v2f dxB = pxB * s.x + s.z;
        const v2f r2A = dyA * dyA + dxA * dxA;
        const v2f r2B = dyB * dyB + dxB * dxB;
        v2f eA, eB;
        eA.x  = FAST_EXP2(-r2A.x);  eA.y  = FAST_EXP2(-r2A.y);
        eB.x  = FAST_EXP2(-r2B.x);  eB.y  = FAST_EXP2(-r2B.y);
        const v2f riA = rsq_nr2(r2A);         // pk VALU, off the trans pipe
        const v2f riB = rsq_nr2(r2B);
        const v2f fA = (eA * riA) * s.w;      // tau * exp * rsqrt (scaled)
        const v2f fB = (eB * riB) * s.w;
        acc0A += fA * dxA;
        acc1A -= fA * dyA;
        acc0B += fB * dxB;
        acc1B -= fB * dyB;
    }

    red[q][h]       = (v2f){ acc0A.x, acc1A.x };
    red[q][h + 64]  = (v2f){ acc0A.y, acc1A.y };
    red[q][h + 128] = (v2f){ acc0B.x, acc1B.x };
    red[q][h + 192] = (v2f){ acc0B.y, acc1B.y };
    __syncthreads();

    // 512 threads reduce 256 points: thread t handles point t/2's component t&1.
    if (tid < 2 * PTS) {
        const int pt = tid >> 1;
        const int c  = tid & 1;
        float r = red[0][pt][c];
        #pragma unroll
        for (int i = 1; i < NQ; ++i) r += red[i][pt][c];
        out[((size_t)b * 65536 + base + pt) * 2 + c] = r;
    }
}

extern "C" void kernel_launch(void* const* d_in, const int* in_sizes, int n_in,
                              void* d_out, int out_size, void* d_ws, size_t ws_size,
                              hipStream_t stream) {
    const float* vortex = (const float*)d_in[0];  // (2, 512, 6)
    const float* points = (const float*)d_in[1];  // (2, 256, 256, 2)
    float* out = (float*)d_out;                   // (2, 256, 256, 2)

    const int blocks = 2 * (65536 / 256);  // 512 blocks x 512 threads
    GaussianFalloffKernel_83434034692733_kernel<<<blocks, 512, 0, stream>>>(
        vortex, points, out);
}

// Round 3
// 71.157 us; speedup vs baseline: 1.0876x; 1.0876x over previous
//
#include <hip/hip_runtime.h>

typedef float v2f __attribute__((ext_vector_type(2)));

#if defined(__has_builtin) && __has_builtin(__builtin_amdgcn_exp2f)
#  define FAST_EXP2(x) __builtin_amdgcn_exp2f(x)
#else
#  define FAST_EXP2(x) exp2f(x)
#endif
#if defined(__has_builtin) && __has_builtin(__builtin_amdgcn_rsqf)
#  define FAST_RSQ(x) __builtin_amdgcn_rsqf(x)
#else
#  define FAST_RSQ(x) rsqrtf(x)
#endif

// out[b,p,0] =  sum_v tau_v * exp(-r2/sig^2) * rsqrt(r2) * (p1 - x_v)
// out[b,p,1] = -sum_v tau_v * exp(-r2/sig^2) * rsqrt(r2) * (p0 - y_v)
//
// Coordinate pre-scaling (a = sqrt(log2e)/|sig|): dy' = a*(p0-y),
// dx' = a*(p1-x), r2' = dy'^2+dx'^2 -> exp(-r2/sig^2)*rsqrt(r2)*dx =
// exp2(-r2')*rsqrt(r2')*dx' (a cancels); exp negation via src modifier.
//
// R7: NR-rsqrt experiment (R6) FALSIFIED the trans-bound theory: removing
// 4 trans ops and adding ~22 pk-VALU instrs cost +51 cyc/iter (~= the
// added issue cycles). Kernel is bound by total SIMD instruction issue
// (pk_f32 = 4 cyc/wave64, no throughput gain over scalar f32), possibly
// plus dependency/LDS stalls unhidden at 4 waves/SIMD. This round:
// native v_rsq restored; occupancy doubled to 8 waves/SIMD (1024-thread
// blocks, 16 waves, split-K x16, 32 vortices/wave, <=64 VGPR) to test
// the stall hypothesis. Neutral result => issue roofline at throttled
// clock; win => latency-hiding was the residual gap.
__global__ __launch_bounds__(1024, 8)
void GaussianFalloffKernel_83434034692733_kernel(
    const float* __restrict__ vortex,   // (2, 512, 6)
    const float* __restrict__ points,   // (2, 65536, 2)
    float* __restrict__ out)            // (2, 65536, 2)
{
    constexpr int NV  = 512;
    constexpr int NQ  = 16;                // split-K pieces (= waves/block)
    constexpr int VQ  = NV / NQ;           // 32 vortices per wave
    constexpr int PTS = 256;               // points per block (64 lanes x 4)
    constexpr int BPB = 65536 / PTS;       // 256 blocks per batch

    __shared__ float4 sv[NV];              // {a, -a*y, -a*x, tau}, 8 KB
    __shared__ v2f    red[NQ][PTS];        // 32 KB cross-wave partials

    const int b    = blockIdx.x / BPB;
    const int base = (blockIdx.x % BPB) * PTS;
    const int tid  = threadIdx.x;
    const int q    = tid >> 6;             // wave index == vortex slice
    const int h    = tid & 63;             // lane

    // Stage: one vortex per thread (first 512 threads).
    if (tid < NV) {
        const float* __restrict__ p = vortex + ((size_t)b * NV + tid) * 6;
        const float y   = p[0];
        const float x   = p[1];
        const float tau = p[2];
        const float sig = p[3];
        const float a   = 1.2011224087864498f / fabsf(sig);  // sqrt(log2e)/|sig|
        sv[tid] = make_float4(a, -a * y, -a * x, tau);
    }
    __syncthreads();

    // Four points per thread: base + h + {0,64,128,192}, packed SoA.
    const float2* __restrict__ pp =
        (const float2*)points + (size_t)b * 65536 + base;
    const float2 p0 = pp[h];
    const float2 p1 = pp[h + 64];
    const float2 p2 = pp[h + 128];
    const float2 p3 = pp[h + 192];
    const v2f pyA = { p0.x, p1.x }, pxA = { p0.y, p1.y };
    const v2f pyB = { p2.x, p3.x }, pxB = { p2.y, p3.y };

    v2f acc0A = { 0.0f, 0.0f }, acc1A = { 0.0f, 0.0f };
    v2f acc0B = { 0.0f, 0.0f }, acc1B = { 0.0f, 0.0f };

    const float4* __restrict__ svq = sv + q * VQ;
    #pragma unroll 4
    for (int v = 0; v < VQ; ++v) {
        const float4 s = svq[v];              // wave-uniform LDS broadcast
        const v2f dyA = pyA * s.x + s.y;      // a*(p0 - y_v)   (pk_fma)
        const v2f dxA = pxA * s.x + s.z;      // a*(p1 - x_v)
        const v2f dyB = pyB * s.x + s.y;
        const v2f dxB = pxB * s.x + s.z;
        const v2f r2A = dyA * dyA + dxA * dxA;
        const v2f r2B = dyB * dyB + dxB * dxB;
        v2f eA, eB, riA, riB;
        eA.x  = FAST_EXP2(-r2A.x);  eA.y  = FAST_EXP2(-r2A.y);
        eB.x  = FAST_EXP2(-r2B.x);  eB.y  = FAST_EXP2(-r2B.y);
        riA.x = FAST_RSQ(r2A.x);    riA.y = FAST_RSQ(r2A.y);
        riB.x = FAST_RSQ(r2B.x);    riB.y = FAST_RSQ(r2B.y);
        const v2f fA = (eA * riA) * s.w;      // tau * exp * rsqrt (scaled)
        const v2f fB = (eB * riB) * s.w;
        acc0A += fA * dxA;
        acc1A -= fA * dyA;
        acc0B += fB * dxB;
        acc1B -= fB * dyB;
    }

    red[q][h]       = (v2f){ acc0A.x, acc1A.x };
    red[q][h + 64]  = (v2f){ acc0A.y, acc1A.y };
    red[q][h + 128] = (v2f){ acc0B.x, acc1B.x };
    red[q][h + 192] = (v2f){ acc0B.y, acc1B.y };
    __syncthreads();

    // Threads 0..511 reduce: thread t handles point t/2's component t&1.
    if (tid < 2 * PTS) {
        const int pt = tid >> 1;
        const int c  = tid & 1;
        float r = red[0][pt][c];
        #pragma unroll
        for (int i = 1; i < NQ; ++i) r += red[i][pt][c];
        out[((size_t)b * 65536 + base + pt) * 2 + c] = r;
    }
}

extern "C" void kernel_launch(void* const* d_in, const int* in_sizes, int n_in,
                              void* d_out, int out_size, void* d_ws, size_t ws_size,
                              hipStream_t stream) {
    const float* vortex = (const float*)d_in[0];  // (2, 512, 6)
    const float* points = (const float*)d_in[1];  // (2, 256, 256, 2)
    float* out = (float*)d_out;                   // (2, 256, 256, 2)

    const int blocks = 2 * (65536 / 256);  // 512 blocks x 1024 threads
    GaussianFalloffKernel_83434034692733_kernel<<<blocks, 1024, 0, stream>>>(
        vortex, points, out);
}